// Round 2
// baseline (465.180 us; speedup 1.0000x reference)
//
#include <hip/hip_runtime.h>
#include <hip/hip_fp16.h>

typedef _Float16 half8   __attribute__((ext_vector_type(8)));
typedef _Float16 half4_t __attribute__((ext_vector_type(4)));
typedef float    f32x4   __attribute__((ext_vector_type(4)));

#define HDIM  1024
#define BATCH 32
#define TLEN  1024
#define M_TOT (BATCH * TLEN)

#define BM 128
#define BN 128
#define BKF 64   // fast-path K-tile (halves); row = 128 B
#define LDA 40   // fallback-path padded LDS stride (halves)

// ---------------- fused prep: We16 convert (blocks 0..1023), qproj (1024..2047), zero (2048..2175)
__global__ void prep_k(const float* __restrict__ W, const float* __restrict__ hidden,
                       const float* __restrict__ bias, _Float16* __restrict__ We16,
                       float* __restrict__ q, float* __restrict__ energ) {
    const int bid = blockIdx.x;
    const int t = threadIdx.x;
    if (bid < 1024) {
        // We = W[:, H:] -> fp16, g-major k-contiguous
        int idx = bid * 256 + t;
        int g  = idx >> 8;
        int k4 = idx & 255;
        float4 f = *reinterpret_cast<const float4*>(W + (size_t)g * 2048 + 1024 + k4 * 4);
        half4_t h;
        h[0] = (_Float16)f.x; h[1] = (_Float16)f.y; h[2] = (_Float16)f.z; h[3] = (_Float16)f.w;
        *reinterpret_cast<half4_t*>(We16 + (size_t)idx * 4) = h;
    } else if (bid < 2048) {
        // q[b][g] = bias[g] + sum_h hidden[b][h] * W[g][h]
        int g = bid - 1024;
        int wave = t >> 6, lane = t & 63;
        float acc[BATCH];
#pragma unroll
        for (int b = 0; b < BATCH; b++) acc[b] = 0.f;
        const float* wr = W + (size_t)g * 2048;
        for (int h = t; h < HDIM; h += 256) {
            float w = wr[h];
#pragma unroll
            for (int b = 0; b < BATCH; b++) acc[b] = fmaf(w, hidden[b * HDIM + h], acc[b]);
        }
        __shared__ float sm[4 * BATCH];
#pragma unroll
        for (int b = 0; b < BATCH; b++) {
            float s = acc[b];
#pragma unroll
            for (int off = 32; off >= 1; off >>= 1) s += __shfl_xor(s, off);
            if (lane == 0) sm[wave * BATCH + b] = s;
        }
        __syncthreads();
        if (t < BATCH) {
            float s = sm[t] + sm[BATCH + t] + sm[2 * BATCH + t] + sm[3 * BATCH + t];
            q[t * HDIM + g] = s + bias[g];
        }
    } else {
        energ[(bid - 2048) * 256 + t] = 0.f;
    }
}

__device__ __forceinline__ void async16(const void* g, void* l) {
    __builtin_amdgcn_global_load_lds(
        (const __attribute__((address_space(1))) void*)g,
        (__attribute__((address_space(3))) void*)l, 16, 0, 0);
}

// ---------------- FAST: round-0 87us structure + fused fp32->fp16 A conversion ----------
// A staged via registers: 8x global_load_dwordx4 (fp32 enc) issued at loop top (latency
// hidden under frag-reads + barrier + MFMA), converted + ds_write_b128 into the XOR-swizzled
// As layout AFTER the MFMA cluster. B staged via global_load_lds from prepped We16 with
// pre-swizzled global source (unchanged from the verified round-0 kernel).
// Per K-tile sync: frag ds_reads -> lgkmcnt(0) -> barrier1 -> issue B async -> 32 MFMA ->
// [sched fence] -> cvt+ds_write A -> vmcnt(0)+lgkmcnt(0) -> barrier2.
__global__ __launch_bounds__(256)
void attn_gemm_f32a_k(const float* __restrict__ enc,
                      const _Float16* __restrict__ We16,
                      const float* __restrict__ q, const float* __restrict__ v,
                      float* __restrict__ energies) {
    __shared__ _Float16 As[BM * BKF];   // 16 KB, rows of 128 B, chunks XOR-swizzled
    __shared__ _Float16 Bs[BN * BKF];   // 16 KB

    const int tid  = threadIdx.x;
    const int id   = blockIdx.x;
    const int xcd  = id & 7;
    const int w    = id >> 3;
    const int m0   = (xcd * 32 + (w >> 3)) * BM;
    const int n0   = (w & 7) * BN;
    const int wave = tid >> 6;
    const int lane = tid & 63;
    const int quad = lane >> 4;
    const int l16  = lane & 15;
    const int wm   = (wave & 1) * 64;
    const int wn   = (wave >> 1) * 64;

    f32x4 acc[4][4];
#pragma unroll
    for (int i = 0; i < 4; i++)
#pragma unroll
        for (int j = 0; j < 4; j++) acc[i][j] = {0.f, 0.f, 0.f, 0.f};

    // ---- B staging (unchanged): pre-swizzled global source, linear LDS dest ----
    const int srow = wave * 32 + (lane >> 3);
    const int scol = ((lane & 7) ^ (lane >> 3)) * 8;          // halves
    const _Float16* gB = We16 + (size_t)(n0 + srow) * HDIM + scol;
    _Float16* lB = Bs + wave * 2048;
    const size_t istep = (size_t)8 * HDIM;

    // ---- A reg-staging: thread covers rows {p*32 + (tid>>3)}, K-chunk (tid&7)*8 ----
    const int arow_s = tid >> 3;          // 0..31
    const int ac     = tid & 7;
    const float* gA = enc + (size_t)(m0 + arow_s) * HDIM + ac * 8;
    _Float16* aw = As + arow_s * BKF + ((ac ^ (arow_s & 7)) * 8);   // swizzled chunk slot

    float4 fa[4][2];

#define ISSUE_A(kk) { _Pragma("unroll") for (int p_ = 0; p_ < 4; p_++) { \
    const float* s_ = gA + (size_t)(p_ * 32) * HDIM + (kk); \
    fa[p_][0] = *reinterpret_cast<const float4*>(s_); \
    fa[p_][1] = *reinterpret_cast<const float4*>(s_ + 4); } }

#define CVT_WRITE_A() { _Pragma("unroll") for (int p_ = 0; p_ < 4; p_++) { \
    half8 h_; \
    h_[0] = (_Float16)fa[p_][0].x; h_[1] = (_Float16)fa[p_][0].y; \
    h_[2] = (_Float16)fa[p_][0].z; h_[3] = (_Float16)fa[p_][0].w; \
    h_[4] = (_Float16)fa[p_][1].x; h_[5] = (_Float16)fa[p_][1].y; \
    h_[6] = (_Float16)fa[p_][1].z; h_[7] = (_Float16)fa[p_][1].w; \
    *reinterpret_cast<half8*>(aw + p_ * 32 * BKF) = h_; } }

    // ---- frag read offsets: row r wants chunk c=s*4+quad, stored at c^(r&7) ----
    int aoff[2][4], boff[2][4];
#pragma unroll
    for (int s = 0; s < 2; s++)
#pragma unroll
        for (int i = 0; i < 4; i++) {
            int ra = wm + i * 16 + l16;
            int rb = wn + i * 16 + l16;
            aoff[s][i] = ra * BKF + (((s * 4 + quad) ^ (l16 & 7)) * 8);
            boff[s][i] = rb * BKF + (((s * 4 + quad) ^ (l16 & 7)) * 8);
        }

    // ---- prologue: tile 0 ----
    ISSUE_A(0);
#pragma unroll
    for (int ii = 0; ii < 4; ii++) async16(gB + ii * istep, lB + ii * 512);
    CVT_WRITE_A();                                  // compiler waits vmcnt for fa deps
    asm volatile("s_waitcnt vmcnt(0) lgkmcnt(0)" ::: "memory");
    __builtin_amdgcn_s_barrier();
    __builtin_amdgcn_sched_barrier(0);

    for (int k0 = 0; k0 < HDIM; k0 += BKF) {
        const bool more = (k0 + BKF) < HDIM;
        if (more) ISSUE_A(k0 + BKF);               // early issue: latency hides under below

        half8 af[2][4], bf[2][4];
#pragma unroll
        for (int s = 0; s < 2; s++)
#pragma unroll
            for (int i = 0; i < 4; i++) {
                af[s][i] = *reinterpret_cast<const half8*>(&As[aoff[s][i]]);
                bf[s][i] = *reinterpret_cast<const half8*>(&Bs[boff[s][i]]);
            }
        asm volatile("s_waitcnt lgkmcnt(0)" ::: "memory");   // frags in regs
        __builtin_amdgcn_sched_barrier(0);
        __builtin_amdgcn_s_barrier();                        // all waves done reading LDS
        __builtin_amdgcn_sched_barrier(0);

        if (more) {
            const int kn = k0 + BKF;
#pragma unroll
            for (int ii = 0; ii < 4; ii++) async16(gB + kn + ii * istep, lB + ii * 512);
        }

#pragma unroll
        for (int s = 0; s < 2; s++)
#pragma unroll
            for (int mi = 0; mi < 4; mi++)
#pragma unroll
                for (int ni = 0; ni < 4; ni++)
                    acc[mi][ni] = __builtin_amdgcn_mfma_f32_16x16x32_f16(af[s][mi], bf[s][ni], acc[mi][ni], 0, 0, 0);

        __builtin_amdgcn_sched_barrier(0);          // keep cvt/write after MFMA cluster

        if (more) {
            CVT_WRITE_A();                          // compiler inserts vmcnt(4): A landed, B in flight
            asm volatile("s_waitcnt vmcnt(0) lgkmcnt(0)" ::: "memory");  // B asyncs + ds_writes done
            __builtin_amdgcn_s_barrier();
            __builtin_amdgcn_sched_barrier(0);
        }
    }
#undef ISSUE_A
#undef CVT_WRITE_A

    // epilogue: C/D col = l16, row = quad*4 + r
    const int bidx = m0 >> 10;
    float qv[4], vv[4];
#pragma unroll
    for (int ni = 0; ni < 4; ni++) {
        int g = n0 + wn + ni * 16 + l16;
        qv[ni] = q[bidx * HDIM + g];
        vv[ni] = v[g];
    }
#pragma unroll
    for (int mi = 0; mi < 4; mi++) {
#pragma unroll
        for (int r = 0; r < 4; r++) {
            int row = wm + mi * 16 + quad * 4 + r;
            float s = 0.f;
#pragma unroll
            for (int ni = 0; ni < 4; ni++) {
                float pre = acc[mi][ni][r] + qv[ni];
                float e = __expf(2.f * pre);
                float th = 1.f - 2.f / (e + 1.f);
                s = fmaf(th, vv[ni], s);
            }
            s += __shfl_xor(s, 1);
            s += __shfl_xor(s, 2);
            s += __shfl_xor(s, 4);
            s += __shfl_xor(s, 8);
            if (l16 == 0) atomicAdd(&energies[m0 + row], s);
        }
    }
}

// ---------------- FALLBACK: fp32 A on-the-fly convert (BK=32, padded LDS) ----------------
__global__ __launch_bounds__(256, 2)
void attn_gemm_k(const float* __restrict__ enc, const _Float16* __restrict__ We16,
                 const float* __restrict__ q, const float* __restrict__ v,
                 float* __restrict__ energies) {
    __shared__ _Float16 As[BM * LDA];
    __shared__ _Float16 Bs[BN * LDA];

    const int tid  = threadIdx.x;
    const int m0   = blockIdx.x * BM;
    const int n0   = blockIdx.y * BN;
    const int wave = tid >> 6;
    const int lane = tid & 63;
    const int quad = lane >> 4;
    const int l16  = lane & 15;
    const int wm   = (wave & 1) * 64;
    const int wn   = (wave >> 1) * 64;

    const int srow = tid >> 1;
    const int scol = (tid & 1) * 16;

    f32x4 acc[4][4];
#pragma unroll
    for (int i = 0; i < 4; i++)
#pragma unroll
        for (int j = 0; j < 4; j++) acc[i][j] = {0.f, 0.f, 0.f, 0.f};

    const float*    ag = enc  + (size_t)(m0 + srow) * HDIM + scol;
    const _Float16* bg = We16 + (size_t)(n0 + srow) * HDIM + scol;
    _Float16* aw = &As[srow * LDA + scol];
    _Float16* bw = &Bs[srow * LDA + scol];

    for (int k0 = 0; k0 < HDIM; k0 += 32) {
        float4 a0 = *reinterpret_cast<const float4*>(ag + k0 + 0);
        float4 a1 = *reinterpret_cast<const float4*>(ag + k0 + 4);
        float4 a2 = *reinterpret_cast<const float4*>(ag + k0 + 8);
        float4 a3 = *reinterpret_cast<const float4*>(ag + k0 + 12);
        float4 b0 = *reinterpret_cast<const float4*>(bg + k0);
        float4 b1 = *reinterpret_cast<const float4*>(bg + k0 + 8);

        __syncthreads();

        half8 ha0, ha1;
        ha0[0] = (_Float16)a0.x; ha0[1] = (_Float16)a0.y; ha0[2] = (_Float16)a0.z; ha0[3] = (_Float16)a0.w;
        ha0[4] = (_Float16)a1.x; ha0[5] = (_Float16)a1.y; ha0[6] = (_Float16)a1.z; ha0[7] = (_Float16)a1.w;
        ha1[0] = (_Float16)a2.x; ha1[1] = (_Float16)a2.y; ha1[2] = (_Float16)a2.z; ha1[3] = (_Float16)a2.w;
        ha1[4] = (_Float16)a3.x; ha1[5] = (_Float16)a3.y; ha1[6] = (_Float16)a3.z; ha1[7] = (_Float16)a3.w;
        *reinterpret_cast<half8*>(aw)     = ha0;
        *reinterpret_cast<half8*>(aw + 8) = ha1;
        *reinterpret_cast<float4*>(bw)     = b0;
        *reinterpret_cast<float4*>(bw + 8) = b1;

        __syncthreads();

        half8 af[4], bf[4];
#pragma unroll
        for (int i = 0; i < 4; i++) {
            af[i] = *reinterpret_cast<const half8*>(&As[(wm + i * 16 + l16) * LDA + quad * 8]);
            bf[i] = *reinterpret_cast<const half8*>(&Bs[(wn + i * 16 + l16) * LDA + quad * 8]);
        }
#pragma unroll
        for (int mi = 0; mi < 4; mi++)
#pragma unroll
            for (int ni = 0; ni < 4; ni++)
                acc[mi][ni] = __builtin_amdgcn_mfma_f32_16x16x32_f16(af[mi], bf[ni], acc[mi][ni], 0, 0, 0);
    }

    const int bidx = m0 >> 10;
    float qv[4], vv[4];
#pragma unroll
    for (int ni = 0; ni < 4; ni++) {
        int g = n0 + wn + ni * 16 + l16;
        qv[ni] = q[bidx * HDIM + g];
        vv[ni] = v[g];
    }
#pragma unroll
    for (int mi = 0; mi < 4; mi++) {
#pragma unroll
        for (int r = 0; r < 4; r++) {
            int row = wm + mi * 16 + quad * 4 + r;
            float s = 0.f;
#pragma unroll
            for (int ni = 0; ni < 4; ni++) {
                float pre = acc[mi][ni][r] + qv[ni];
                float e = __expf(2.f * pre);
                float th = 1.f - 2.f / (e + 1.f);
                s = fmaf(th, vv[ni], s);
            }
            s += __shfl_xor(s, 1);
            s += __shfl_xor(s, 2);
            s += __shfl_xor(s, 4);
            s += __shfl_xor(s, 8);
            if (l16 == 0) atomicAdd(&energies[m0 + row], s);
        }
    }
}

// ---------------- softmax over t per batch row ----------------
__global__ void softmax_k(const float* __restrict__ energies, float* __restrict__ out) {
    int b = blockIdx.x;
    int t = threadIdx.x;
    int wave = t >> 6, lane = t & 63;
    __shared__ float smax[4], ssum[4];
    float e[4];
#pragma unroll
    for (int i = 0; i < 4; i++) e[i] = energies[b * TLEN + t + i * 256];
    float m = fmaxf(fmaxf(e[0], e[1]), fmaxf(e[2], e[3]));
#pragma unroll
    for (int off = 32; off >= 1; off >>= 1) m = fmaxf(m, __shfl_xor(m, off));
    if (lane == 0) smax[wave] = m;
    __syncthreads();
    float M = fmaxf(fmaxf(smax[0], smax[1]), fmaxf(smax[2], smax[3]));
    float x[4]; float s = 0.f;
#pragma unroll
    for (int i = 0; i < 4; i++) { x[i] = __expf(e[i] - M); s += x[i]; }
#pragma unroll
    for (int off = 32; off >= 1; off >>= 1) s += __shfl_xor(s, off);
    if (lane == 0) ssum[wave] = s;
    __syncthreads();
    float S = ssum[0] + ssum[1] + ssum[2] + ssum[3];
    float inv = 1.f / S;
#pragma unroll
    for (int i = 0; i < 4; i++) out[b * TLEN + t + i * 256] = x[i] * inv;
}

extern "C" void kernel_launch(void* const* d_in, const int* in_sizes, int n_in,
                              void* d_out, int out_size, void* d_ws, size_t ws_size,
                              hipStream_t stream) {
    const float* hidden = (const float*)d_in[0];   // (1, 32, 1024) fp32
    const float* enc    = (const float*)d_in[1];   // (32, 1024, 1024) fp32
    const float* W      = (const float*)d_in[2];   // (1024, 2048) fp32
    const float* bias   = (const float*)d_in[3];   // (1024,) fp32
    const float* v      = (const float*)d_in[4];   // (1024,) fp32
    float* out = (float*)d_out;                    // (32, 1, 1024) fp32

    char* ws = (char*)d_ws;
    float*    q     = (float*)ws;                  // 128 KB
    float*    energ = (float*)(ws + 131072);       // 128 KB
    _Float16* We16  = (_Float16*)(ws + 262144);    // 2 MB
    const size_t need_fast = 262144 + 2097152;     // ~2.4 MB

    // prep: blocks 0..1023 we_convert, 1024..2047 qproj, 2048..2175 zero energies
    prep_k<<<dim3(2176), 256, 0, stream>>>(W, hidden, bias, We16, q, energ);
    if (ws_size >= need_fast) {
        attn_gemm_f32a_k<<<dim3(2048), 256, 0, stream>>>(enc, We16, q, v, energ);
    } else {
        attn_gemm_k<<<dim3(256, 8), 256, 0, stream>>>(enc, We16, q, v, energ);
    }
    softmax_k<<<dim3(BATCH), 256, 0, stream>>>(energ, out);
}

// Round 3
// 333.149 us; speedup vs baseline: 1.3963x; 1.3963x over previous
//
#include <hip/hip_runtime.h>
#include <hip/hip_fp16.h>

typedef _Float16 half8   __attribute__((ext_vector_type(8)));
typedef _Float16 half4_t __attribute__((ext_vector_type(4)));
typedef float    f32x4   __attribute__((ext_vector_type(4)));

#define HDIM  1024
#define BATCH 32
#define TLEN  1024
#define M_TOT (BATCH * TLEN)

#define BM 128
#define BN 128
#define BKF 64   // K-tile (elements); A row = 256 B fp32, B row = 128 B fp16
#define LDA 40   // fallback-path padded LDS stride (halves)

// ---------------- fused prep: We16 convert (blocks 0..1023), qproj (1024..2047), zero (2048..2175)
__global__ void prep_k(const float* __restrict__ W, const float* __restrict__ hidden,
                       const float* __restrict__ bias, _Float16* __restrict__ We16,
                       float* __restrict__ q, float* __restrict__ energ) {
    const int bid = blockIdx.x;
    const int t = threadIdx.x;
    if (bid < 1024) {
        // We = W[:, H:] -> fp16, g-major k-contiguous
        int idx = bid * 256 + t;
        int g  = idx >> 8;
        int k4 = idx & 255;
        float4 f = *reinterpret_cast<const float4*>(W + (size_t)g * 2048 + 1024 + k4 * 4);
        half4_t h;
        h[0] = (_Float16)f.x; h[1] = (_Float16)f.y; h[2] = (_Float16)f.z; h[3] = (_Float16)f.w;
        *reinterpret_cast<half4_t*>(We16 + (size_t)idx * 4) = h;
    } else if (bid < 2048) {
        // q[b][g] = bias[g] + sum_h hidden[b][h] * W[g][h]
        int g = bid - 1024;
        int wave = t >> 6, lane = t & 63;
        float acc[BATCH];
#pragma unroll
        for (int b = 0; b < BATCH; b++) acc[b] = 0.f;
        const float* wr = W + (size_t)g * 2048;
        for (int h = t; h < HDIM; h += 256) {
            float w = wr[h];
#pragma unroll
            for (int b = 0; b < BATCH; b++) acc[b] = fmaf(w, hidden[b * HDIM + h], acc[b]);
        }
        __shared__ float sm[4 * BATCH];
#pragma unroll
        for (int b = 0; b < BATCH; b++) {
            float s = acc[b];
#pragma unroll
            for (int off = 32; off >= 1; off >>= 1) s += __shfl_xor(s, off);
            if (lane == 0) sm[wave * BATCH + b] = s;
        }
        __syncthreads();
        if (t < BATCH) {
            float s = sm[t] + sm[BATCH + t] + sm[2 * BATCH + t] + sm[3 * BATCH + t];
            q[t * HDIM + g] = s + bias[g];
        }
    } else {
        energ[(bid - 2048) * 256 + t] = 0.f;
    }
}

__device__ __forceinline__ void async16(const void* g, void* l) {
    __builtin_amdgcn_global_load_lds(
        (const __attribute__((address_space(1))) void*)g,
        (__attribute__((address_space(3))) void*)l, 16, 0, 0);
}

// ---------------- FAST: round-0 structure, A staged as fp32 DIRECTLY from enc ----------
// Identical loop skeleton to the verified 87us kernel (frag reads -> sync -> issue asyncs
// -> 32 MFMA -> sync). Differences:
//   * As is fp32 (32 KB), staged via global_load_lds straight from enc (no convert kernel).
//   * A chunk swizzle: 16-B chunk c of row r stored at slot c ^ (r&15); applied on the
//     GLOBAL source address (linear LDS dest) and inverted at frag-read time.
//   * A fragments read as 2x ds_read_b128 fp32 + packed cvt to half8 (VALU headroom: round-0
//     VALUBusy was 41%).
// Bank check: within a 16-lane group quad is constant, so slot = (c0 ^ l16) is a bijection
// over the 16 chunks of a 256-B row -> only the free 2-way aliasing (same as B path).
__global__ __launch_bounds__(256)
void attn_gemm_f32d_k(const float* __restrict__ enc,
                      const _Float16* __restrict__ We16,
                      const float* __restrict__ q, const float* __restrict__ v,
                      float* __restrict__ energies) {
    __shared__ float    Asf[BM * BKF];   // 32 KB fp32
    __shared__ _Float16 Bs[BN * BKF];    // 16 KB fp16

    const int tid  = threadIdx.x;
    const int id   = blockIdx.x;
    const int xcd  = id & 7;
    const int w    = id >> 3;
    const int m0   = (xcd * 32 + (w >> 3)) * BM;
    const int n0   = (w & 7) * BN;
    const int wave = tid >> 6;
    const int lane = tid & 63;
    const int quad = lane >> 4;
    const int l16  = lane & 15;
    const int wm   = (wave & 1) * 64;
    const int wn   = (wave >> 1) * 64;

    f32x4 acc[4][4];
#pragma unroll
    for (int i = 0; i < 4; i++)
#pragma unroll
        for (int j = 0; j < 4; j++) acc[i][j] = {0.f, 0.f, 0.f, 0.f};

    // ---- B staging (verified round-0 path): pre-swizzled global source, linear LDS dest
    const int srowB = wave * 32 + (lane >> 3);
    const int scolB = ((lane & 7) ^ (lane >> 3)) * 8;          // halves
    const _Float16* gB = We16 + (size_t)(n0 + srowB) * HDIM + scolB;
    _Float16* lB = Bs + wave * 2048;
    const size_t istepB = (size_t)8 * HDIM;

    // ---- A staging fp32: issue ii writes rows [wave*32+ii*4, +4); lane covers
    // row_local lr = lane>>4, slot chunk cA = lane&15; global chunk = cA ^ ((ii*4+lr)&15)
    const int lr = lane >> 4;
    const int cA = lane & 15;
    const float* pA[4];
#pragma unroll
    for (int j = 0; j < 4; j++)
        pA[j] = enc + (size_t)(m0 + wave * 32 + lr) * HDIM + ((cA ^ (j * 4 + lr)) * 4);
    float* lA = Asf + wave * 2048;     // + ii*256 floats per issue (wave-uniform)

    // ---- frag read offsets ----
    // B: row rb wants 16B chunk (s*4+quad), stored at chunk ^ (rb&7); rb&7 == l16&7
    int boff[2][4];
#pragma unroll
    for (int s = 0; s < 2; s++)
#pragma unroll
        for (int i = 0; i < 4; i++)
            boff[s][i] = (wn + i * 16 + l16) * BKF + (((s * 4 + quad) ^ (l16 & 7)) * 8);
    // A: row ra wants fp32 chunks c0=(s*4+quad)*2 and c0+1, stored at chunk ^ (ra&15); ra&15==l16
    int arow[4];
#pragma unroll
    for (int i = 0; i < 4; i++) arow[i] = (wm + i * 16 + l16) * BKF;
    int acol[2][2];
#pragma unroll
    for (int s = 0; s < 2; s++)
#pragma unroll
        for (int j = 0; j < 2; j++)
            acol[s][j] = ((((s * 4 + quad) * 2 + j) ^ l16) * 4);

    // ---- prologue: stage tile 0 ----
#pragma unroll
    for (int ii = 0; ii < 8; ii++)
        async16(pA[ii & 3] + (size_t)(ii * 4) * HDIM, lA + ii * 256);
#pragma unroll
    for (int ii = 0; ii < 4; ii++)
        async16(gB + ii * istepB, lB + ii * 512);
    __syncthreads();

    for (int k0 = 0; k0 < HDIM; k0 += BKF) {
        half8 af[2][4], bf[2][4];
#pragma unroll
        for (int s = 0; s < 2; s++)
#pragma unroll
            for (int i = 0; i < 4; i++) {
                f32x4 a0 = *reinterpret_cast<const f32x4*>(&Asf[arow[i] + acol[s][0]]);
                f32x4 a1 = *reinterpret_cast<const f32x4*>(&Asf[arow[i] + acol[s][1]]);
                half8 h;
                h[0] = (_Float16)a0[0]; h[1] = (_Float16)a0[1];
                h[2] = (_Float16)a0[2]; h[3] = (_Float16)a0[3];
                h[4] = (_Float16)a1[0]; h[5] = (_Float16)a1[1];
                h[6] = (_Float16)a1[2]; h[7] = (_Float16)a1[3];
                af[s][i] = h;
                bf[s][i] = *reinterpret_cast<const half8*>(&Bs[boff[s][i]]);
            }
        __syncthreads();   // all waves done reading LDS (drains lgkmcnt)

        if (k0 + BKF < HDIM) {
            const int kn = k0 + BKF;
#pragma unroll
            for (int ii = 0; ii < 8; ii++)
                async16(pA[ii & 3] + (size_t)(ii * 4) * HDIM + kn, lA + ii * 256);
#pragma unroll
            for (int ii = 0; ii < 4; ii++)
                async16(gB + kn + ii * istepB, lB + ii * 512);
        }

#pragma unroll
        for (int s = 0; s < 2; s++)
#pragma unroll
            for (int mi = 0; mi < 4; mi++)
#pragma unroll
                for (int ni = 0; ni < 4; ni++)
                    acc[mi][ni] = __builtin_amdgcn_mfma_f32_16x16x32_f16(af[s][mi], bf[s][ni], acc[mi][ni], 0, 0, 0);

        __syncthreads();   // drains vmcnt -> next tile valid
    }

    // epilogue: C/D col = l16, row = quad*4 + r (verified)
    const int bidx = m0 >> 10;
    float qv[4], vv[4];
#pragma unroll
    for (int ni = 0; ni < 4; ni++) {
        int g = n0 + wn + ni * 16 + l16;
        qv[ni] = q[bidx * HDIM + g];
        vv[ni] = v[g];
    }
#pragma unroll
    for (int mi = 0; mi < 4; mi++) {
#pragma unroll
        for (int r = 0; r < 4; r++) {
            int row = wm + mi * 16 + quad * 4 + r;
            float s = 0.f;
#pragma unroll
            for (int ni = 0; ni < 4; ni++) {
                float pre = acc[mi][ni][r] + qv[ni];
                float e = __expf(2.f * pre);
                float th = 1.f - 2.f / (e + 1.f);
                s = fmaf(th, vv[ni], s);
            }
            s += __shfl_xor(s, 1);
            s += __shfl_xor(s, 2);
            s += __shfl_xor(s, 4);
            s += __shfl_xor(s, 8);
            if (l16 == 0) atomicAdd(&energies[m0 + row], s);
        }
    }
}

// ---------------- FALLBACK: fp32 A on-the-fly convert (BK=32, padded LDS) ----------------
__global__ __launch_bounds__(256, 2)
void attn_gemm_k(const float* __restrict__ enc, const _Float16* __restrict__ We16,
                 const float* __restrict__ q, const float* __restrict__ v,
                 float* __restrict__ energies) {
    __shared__ _Float16 As[BM * LDA];
    __shared__ _Float16 Bs[BN * LDA];

    const int tid  = threadIdx.x;
    const int m0   = blockIdx.x * BM;
    const int n0   = blockIdx.y * BN;
    const int wave = tid >> 6;
    const int lane = tid & 63;
    const int quad = lane >> 4;
    const int l16  = lane & 15;
    const int wm   = (wave & 1) * 64;
    const int wn   = (wave >> 1) * 64;

    const int srow = tid >> 1;
    const int scol = (tid & 1) * 16;

    f32x4 acc[4][4];
#pragma unroll
    for (int i = 0; i < 4; i++)
#pragma unroll
        for (int j = 0; j < 4; j++) acc[i][j] = {0.f, 0.f, 0.f, 0.f};

    const float*    ag = enc  + (size_t)(m0 + srow) * HDIM + scol;
    const _Float16* bg = We16 + (size_t)(n0 + srow) * HDIM + scol;
    _Float16* aw = &As[srow * LDA + scol];
    _Float16* bw = &Bs[srow * LDA + scol];

    for (int k0 = 0; k0 < HDIM; k0 += 32) {
        float4 a0 = *reinterpret_cast<const float4*>(ag + k0 + 0);
        float4 a1 = *reinterpret_cast<const float4*>(ag + k0 + 4);
        float4 a2 = *reinterpret_cast<const float4*>(ag + k0 + 8);
        float4 a3 = *reinterpret_cast<const float4*>(ag + k0 + 12);
        float4 b0 = *reinterpret_cast<const float4*>(bg + k0);
        float4 b1 = *reinterpret_cast<const float4*>(bg + k0 + 8);

        __syncthreads();

        half8 ha0, ha1;
        ha0[0] = (_Float16)a0.x; ha0[1] = (_Float16)a0.y; ha0[2] = (_Float16)a0.z; ha0[3] = (_Float16)a0.w;
        ha0[4] = (_Float16)a1.x; ha0[5] = (_Float16)a1.y; ha0[6] = (_Float16)a1.z; ha0[7] = (_Float16)a1.w;
        ha1[0] = (_Float16)a2.x; ha1[1] = (_Float16)a2.y; ha1[2] = (_Float16)a2.z; ha1[3] = (_Float16)a2.w;
        ha1[4] = (_Float16)a3.x; ha1[5] = (_Float16)a3.y; ha1[6] = (_Float16)a3.z; ha1[7] = (_Float16)a3.w;
        *reinterpret_cast<half8*>(aw)     = ha0;
        *reinterpret_cast<half8*>(aw + 8) = ha1;
        *reinterpret_cast<float4*>(bw)     = b0;
        *reinterpret_cast<float4*>(bw + 8) = b1;

        __syncthreads();

        half8 af[4], bf[4];
#pragma unroll
        for (int i = 0; i < 4; i++) {
            af[i] = *reinterpret_cast<const half8*>(&As[(wm + i * 16 + l16) * LDA + quad * 8]);
            bf[i] = *reinterpret_cast<const half8*>(&Bs[(wn + i * 16 + l16) * LDA + quad * 8]);
        }
#pragma unroll
        for (int mi = 0; mi < 4; mi++)
#pragma unroll
            for (int ni = 0; ni < 4; ni++)
                acc[mi][ni] = __builtin_amdgcn_mfma_f32_16x16x32_f16(af[mi], bf[ni], acc[mi][ni], 0, 0, 0);
    }

    const int bidx = m0 >> 10;
    float qv[4], vv[4];
#pragma unroll
    for (int ni = 0; ni < 4; ni++) {
        int g = n0 + wn + ni * 16 + l16;
        qv[ni] = q[bidx * HDIM + g];
        vv[ni] = v[g];
    }
#pragma unroll
    for (int mi = 0; mi < 4; mi++) {
#pragma unroll
        for (int r = 0; r < 4; r++) {
            int row = wm + mi * 16 + quad * 4 + r;
            float s = 0.f;
#pragma unroll
            for (int ni = 0; ni < 4; ni++) {
                float pre = acc[mi][ni][r] + qv[ni];
                float e = __expf(2.f * pre);
                float th = 1.f - 2.f / (e + 1.f);
                s = fmaf(th, vv[ni], s);
            }
            s += __shfl_xor(s, 1);
            s += __shfl_xor(s, 2);
            s += __shfl_xor(s, 4);
            s += __shfl_xor(s, 8);
            if (l16 == 0) atomicAdd(&energies[m0 + row], s);
        }
    }
}

// ---------------- softmax over t per batch row ----------------
__global__ void softmax_k(const float* __restrict__ energies, float* __restrict__ out) {
    int b = blockIdx.x;
    int t = threadIdx.x;
    int wave = t >> 6, lane = t & 63;
    __shared__ float smax[4], ssum[4];
    float e[4];
#pragma unroll
    for (int i = 0; i < 4; i++) e[i] = energies[b * TLEN + t + i * 256];
    float m = fmaxf(fmaxf(e[0], e[1]), fmaxf(e[2], e[3]));
#pragma unroll
    for (int off = 32; off >= 1; off >>= 1) m = fmaxf(m, __shfl_xor(m, off));
    if (lane == 0) smax[wave] = m;
    __syncthreads();
    float M = fmaxf(fmaxf(smax[0], smax[1]), fmaxf(smax[2], smax[3]));
    float x[4]; float s = 0.f;
#pragma unroll
    for (int i = 0; i < 4; i++) { x[i] = __expf(e[i] - M); s += x[i]; }
#pragma unroll
    for (int off = 32; off >= 1; off >>= 1) s += __shfl_xor(s, off);
    if (lane == 0) ssum[wave] = s;
    __syncthreads();
    float S = ssum[0] + ssum[1] + ssum[2] + ssum[3];
    float inv = 1.f / S;
#pragma unroll
    for (int i = 0; i < 4; i++) out[b * TLEN + t + i * 256] = x[i] * inv;
}

extern "C" void kernel_launch(void* const* d_in, const int* in_sizes, int n_in,
                              void* d_out, int out_size, void* d_ws, size_t ws_size,
                              hipStream_t stream) {
    const float* hidden = (const float*)d_in[0];   // (1, 32, 1024) fp32
    const float* enc    = (const float*)d_in[1];   // (32, 1024, 1024) fp32
    const float* W      = (const float*)d_in[2];   // (1024, 2048) fp32
    const float* bias   = (const float*)d_in[3];   // (1024,) fp32
    const float* v      = (const float*)d_in[4];   // (1024,) fp32
    float* out = (float*)d_out;                    // (32, 1, 1024) fp32

    char* ws = (char*)d_ws;
    float*    q     = (float*)ws;                  // 128 KB
    float*    energ = (float*)(ws + 131072);       // 128 KB
    _Float16* We16  = (_Float16*)(ws + 262144);    // 2 MB
    const size_t need = 262144 + 2097152;          // ~2.4 MB

    // prep: blocks 0..1023 we_convert, 1024..2047 qproj, 2048..2175 zero energies
    prep_k<<<dim3(2176), 256, 0, stream>>>(W, hidden, bias, We16, q, energ);
    if (ws_size >= need) {
        attn_gemm_f32d_k<<<dim3(2048), 256, 0, stream>>>(enc, We16, q, v, energ);
    } else {
        attn_gemm_k<<<dim3(256, 8), 256, 0, stream>>>(enc, We16, q, v, energ);
    }
    softmax_k<<<dim3(BATCH), 256, 0, stream>>>(energ, out);
}

// Round 5
// 297.394 us; speedup vs baseline: 1.5642x; 1.1202x over previous
//
#include <hip/hip_runtime.h>
#include <hip/hip_fp16.h>

typedef _Float16 half8   __attribute__((ext_vector_type(8)));
typedef _Float16 half4_t __attribute__((ext_vector_type(4)));
typedef float    f32x4   __attribute__((ext_vector_type(4)));

#define HDIM  1024
#define BATCH 32
#define TLEN  1024
#define M_TOT (BATCH * TLEN)

#define BM 128
#define BN 128
#define BKF 64   // fast-path K-tile (halves); row = 128 B
#define LDA 40   // fallback-path padded LDS stride (halves)

// ---------------- merged prep:
//   blocks 0..1023     : We = W[:,H:] -> fp16 (g-major, k-contiguous)
//   blocks 1024..2047  : qproj  q[b][g] = bias[g] + sum_h hidden[b][h]*W[g][h]
//   blocks 2048..18431 : enc fp32 -> fp16 streaming convert (fast path only)
__global__ void prep_k(const float* __restrict__ W, const float* __restrict__ hidden,
                       const float* __restrict__ bias, const float* __restrict__ enc,
                       _Float16* __restrict__ We16, float* __restrict__ q,
                       _Float16* __restrict__ enc16) {
    const int bid = blockIdx.x;
    const int t = threadIdx.x;
    if (bid < 1024) {
        int idx = bid * 256 + t;
        int g  = idx >> 8;
        int k4 = idx & 255;
        float4 f = *reinterpret_cast<const float4*>(W + (size_t)g * 2048 + 1024 + k4 * 4);
        half4_t h;
        h[0] = (_Float16)f.x; h[1] = (_Float16)f.y; h[2] = (_Float16)f.z; h[3] = (_Float16)f.w;
        *reinterpret_cast<half4_t*>(We16 + (size_t)idx * 4) = h;
    } else if (bid < 2048) {
        int g = bid - 1024;
        int wave = t >> 6, lane = t & 63;
        float acc[BATCH];
#pragma unroll
        for (int b = 0; b < BATCH; b++) acc[b] = 0.f;
        const float* wr = W + (size_t)g * 2048;
        for (int h = t; h < HDIM; h += 256) {
            float w = wr[h];
#pragma unroll
            for (int b = 0; b < BATCH; b++) acc[b] = fmaf(w, hidden[b * HDIM + h], acc[b]);
        }
        __shared__ float sm[4 * BATCH];
#pragma unroll
        for (int b = 0; b < BATCH; b++) {
            float s = acc[b];
#pragma unroll
            for (int off = 32; off >= 1; off >>= 1) s += __shfl_xor(s, off);
            if (lane == 0) sm[wave * BATCH + b] = s;
        }
        __syncthreads();
        if (t < BATCH) {
            float s = sm[t] + sm[BATCH + t] + sm[2 * BATCH + t] + sm[3 * BATCH + t];
            q[t * HDIM + g] = s + bias[g];
        }
    } else {
        // enc fp32 -> fp16, 8 elements/thread
        size_t i = ((size_t)(bid - 2048) * 256 + t) * 8;
        float4 f0 = *reinterpret_cast<const float4*>(enc + i);
        float4 f1 = *reinterpret_cast<const float4*>(enc + i + 4);
        half8 h;
        h[0] = (_Float16)f0.x; h[1] = (_Float16)f0.y; h[2] = (_Float16)f0.z; h[3] = (_Float16)f0.w;
        h[4] = (_Float16)f1.x; h[5] = (_Float16)f1.y; h[6] = (_Float16)f1.z; h[7] = (_Float16)f1.w;
        *reinterpret_cast<half8*>(enc16 + i) = h;
    }
}

__device__ __forceinline__ void async16(const void* g, void* l) {
    __builtin_amdgcn_global_load_lds(
        (const __attribute__((address_space(1))) void*)g,
        (__attribute__((address_space(3))) void*)l, 16, 0, 0);
}

// ---------------- FAST: verified round-0 structure (87us). BK=64, XOR-swizzled LDS,
// issue-early staging, XCD-aware remap. Epilogue: 16 partials per row — slot
// (m)*16 + nblk*2 + (wn>>6). Each slot has EXACTLY ONE writer (two waves share a row:
// wn=0 covers n-cols [0,64), wn=64 covers [64,128) — round 4's race is resolved by
// splitting the slot on wn, not by merging).
__global__ __launch_bounds__(256)
void attn_gemm_lds_k(const _Float16* __restrict__ enc16,
                     const _Float16* __restrict__ We16,
                     const float* __restrict__ q, const float* __restrict__ v,
                     float* __restrict__ energ) {
    __shared__ _Float16 As[BM * BKF];   // 16 KB, rows of 128 B, chunks XOR-swizzled
    __shared__ _Float16 Bs[BN * BKF];   // 16 KB

    const int tid  = threadIdx.x;
    const int id   = blockIdx.x;
    const int xcd  = id & 7;
    const int w    = id >> 3;
    const int m0   = (xcd * 32 + (w >> 3)) * BM;
    const int n0   = (w & 7) * BN;
    const int nblk = w & 7;
    const int wave = tid >> 6;
    const int lane = tid & 63;
    const int quad = lane >> 4;
    const int l16  = lane & 15;
    const int wm   = (wave & 1) * 64;
    const int wn   = (wave >> 1) * 64;

    f32x4 acc[4][4];
#pragma unroll
    for (int i = 0; i < 4; i++)
#pragma unroll
        for (int j = 0; j < 4; j++) acc[i][j] = {0.f, 0.f, 0.f, 0.f};

    // staging: issue ii covers rows wave*32+ii*8 + (lane>>3); fetched chunk c=(lane&7)^(lane>>3)
    const int srow = wave * 32 + (lane >> 3);
    const int scol = ((lane & 7) ^ (lane >> 3)) * 8;          // halves
    const _Float16* gA = enc16 + (size_t)(m0 + srow) * HDIM + scol;
    const _Float16* gB = We16  + (size_t)(n0 + srow) * HDIM + scol;
    _Float16* lA = As + wave * 2048;
    _Float16* lB = Bs + wave * 2048;
    const size_t istep = (size_t)8 * HDIM;

#pragma unroll
    for (int ii = 0; ii < 4; ii++) {
        async16(gA + ii * istep, lA + ii * 512);
        async16(gB + ii * istep, lB + ii * 512);
    }
    __syncthreads();

    // frag read offsets: row r wants chunk c=s*4+quad, stored at c^(r&7)
    int aoff[2][4], boff[2][4];
#pragma unroll
    for (int s = 0; s < 2; s++)
#pragma unroll
        for (int i = 0; i < 4; i++) {
            int ra = wm + i * 16 + l16;
            int rb = wn + i * 16 + l16;
            aoff[s][i] = ra * BKF + (((s * 4 + quad) ^ (l16 & 7)) * 8);
            boff[s][i] = rb * BKF + (((s * 4 + quad) ^ (l16 & 7)) * 8);
        }

    for (int k0 = 0; k0 < HDIM; k0 += BKF) {
        half8 af[2][4], bf[2][4];
#pragma unroll
        for (int s = 0; s < 2; s++)
#pragma unroll
            for (int i = 0; i < 4; i++) {
                af[s][i] = *reinterpret_cast<const half8*>(&As[aoff[s][i]]);
                bf[s][i] = *reinterpret_cast<const half8*>(&Bs[boff[s][i]]);
            }
        __syncthreads();   // all waves done reading LDS

        if (k0 + BKF < HDIM) {
            const int kn = k0 + BKF;
#pragma unroll
            for (int ii = 0; ii < 4; ii++) {
                async16(gA + kn + ii * istep, lA + ii * 512);
                async16(gB + kn + ii * istep, lB + ii * 512);
            }
        }

#pragma unroll
        for (int s = 0; s < 2; s++)
#pragma unroll
            for (int mi = 0; mi < 4; mi++)
#pragma unroll
                for (int ni = 0; ni < 4; ni++)
                    acc[mi][ni] = __builtin_amdgcn_mfma_f32_16x16x32_f16(af[s][mi], bf[s][ni], acc[mi][ni], 0, 0, 0);

        __syncthreads();   // drains vmcnt -> next tile valid
    }

    // epilogue: C/D col = l16, row = quad*4 + r; one writer per slot (no atomics)
    const int bidx = m0 >> 10;
    const int half = wn >> 6;    // 0: n-cols [0,64), 1: [64,128)
    float qv[4], vv[4];
#pragma unroll
    for (int ni = 0; ni < 4; ni++) {
        int g = n0 + wn + ni * 16 + l16;
        qv[ni] = q[bidx * HDIM + g];
        vv[ni] = v[g];
    }
#pragma unroll
    for (int mi = 0; mi < 4; mi++) {
#pragma unroll
        for (int r = 0; r < 4; r++) {
            int row = wm + mi * 16 + quad * 4 + r;
            float s = 0.f;
#pragma unroll
            for (int ni = 0; ni < 4; ni++) {
                float pre = acc[mi][ni][r] + qv[ni];
                float e = __expf(2.f * pre);
                float th = 1.f - 2.f / (e + 1.f);
                s = fmaf(th, vv[ni], s);
            }
            s += __shfl_xor(s, 1);
            s += __shfl_xor(s, 2);
            s += __shfl_xor(s, 4);
            s += __shfl_xor(s, 8);
            if (l16 == 0) energ[(size_t)(m0 + row) * 16 + nblk * 2 + half] = s;
        }
    }
}

// ---------------- FALLBACK: fp32 A on-the-fly convert (BK=32, padded LDS) ----------------
__global__ __launch_bounds__(256, 2)
void attn_gemm_k(const float* __restrict__ enc, const _Float16* __restrict__ We16,
                 const float* __restrict__ q, const float* __restrict__ v,
                 float* __restrict__ energ) {
    __shared__ _Float16 As[BM * LDA];
    __shared__ _Float16 Bs[BN * LDA];

    const int tid  = threadIdx.x;
    const int m0   = blockIdx.x * BM;
    const int n0   = blockIdx.y * BN;
    const int wave = tid >> 6;
    const int lane = tid & 63;
    const int quad = lane >> 4;
    const int l16  = lane & 15;
    const int wm   = (wave & 1) * 64;
    const int wn   = (wave >> 1) * 64;

    const int srow = tid >> 1;
    const int scol = (tid & 1) * 16;

    f32x4 acc[4][4];
#pragma unroll
    for (int i = 0; i < 4; i++)
#pragma unroll
        for (int j = 0; j < 4; j++) acc[i][j] = {0.f, 0.f, 0.f, 0.f};

    const float*    ag = enc  + (size_t)(m0 + srow) * HDIM + scol;
    const _Float16* bg = We16 + (size_t)(n0 + srow) * HDIM + scol;
    _Float16* aw = &As[srow * LDA + scol];
    _Float16* bw = &Bs[srow * LDA + scol];

    for (int k0 = 0; k0 < HDIM; k0 += 32) {
        float4 a0 = *reinterpret_cast<const float4*>(ag + k0 + 0);
        float4 a1 = *reinterpret_cast<const float4*>(ag + k0 + 4);
        float4 a2 = *reinterpret_cast<const float4*>(ag + k0 + 8);
        float4 a3 = *reinterpret_cast<const float4*>(ag + k0 + 12);
        float4 b0 = *reinterpret_cast<const float4*>(bg + k0);
        float4 b1 = *reinterpret_cast<const float4*>(bg + k0 + 8);

        __syncthreads();

        half8 ha0, ha1;
        ha0[0] = (_Float16)a0.x; ha0[1] = (_Float16)a0.y; ha0[2] = (_Float16)a0.z; ha0[3] = (_Float16)a0.w;
        ha0[4] = (_Float16)a1.x; ha0[5] = (_Float16)a1.y; ha0[6] = (_Float16)a1.z; ha0[7] = (_Float16)a1.w;
        ha1[0] = (_Float16)a2.x; ha1[1] = (_Float16)a2.y; ha1[2] = (_Float16)a2.z; ha1[3] = (_Float16)a2.w;
        ha1[4] = (_Float16)a3.x; ha1[5] = (_Float16)a3.y; ha1[6] = (_Float16)a3.z; ha1[7] = (_Float16)a3.w;
        *reinterpret_cast<half8*>(aw)     = ha0;
        *reinterpret_cast<half8*>(aw + 8) = ha1;
        *reinterpret_cast<float4*>(bw)     = b0;
        *reinterpret_cast<float4*>(bw + 8) = b1;

        __syncthreads();

        half8 af[4], bf[4];
#pragma unroll
        for (int i = 0; i < 4; i++) {
            af[i] = *reinterpret_cast<const half8*>(&As[(wm + i * 16 + l16) * LDA + quad * 8]);
            bf[i] = *reinterpret_cast<const half8*>(&Bs[(wn + i * 16 + l16) * LDA + quad * 8]);
        }
#pragma unroll
        for (int mi = 0; mi < 4; mi++)
#pragma unroll
            for (int ni = 0; ni < 4; ni++)
                acc[mi][ni] = __builtin_amdgcn_mfma_f32_16x16x32_f16(af[mi], bf[ni], acc[mi][ni], 0, 0, 0);
    }

    const int bidx = m0 >> 10;
    const int half = wn >> 6;
    float qv[4], vv[4];
#pragma unroll
    for (int ni = 0; ni < 4; ni++) {
        int g = n0 + wn + ni * 16 + l16;
        qv[ni] = q[bidx * HDIM + g];
        vv[ni] = v[g];
    }
#pragma unroll
    for (int mi = 0; mi < 4; mi++) {
#pragma unroll
        for (int r = 0; r < 4; r++) {
            int row = wm + mi * 16 + quad * 4 + r;
            float s = 0.f;
#pragma unroll
            for (int ni = 0; ni < 4; ni++) {
                float pre = acc[mi][ni][r] + qv[ni];
                float e = __expf(2.f * pre);
                float th = 1.f - 2.f / (e + 1.f);
                s = fmaf(th, vv[ni], s);
            }
            s += __shfl_xor(s, 1);
            s += __shfl_xor(s, 2);
            s += __shfl_xor(s, 4);
            s += __shfl_xor(s, 8);
            if (l16 == 0) energ[(size_t)(m0 + row) * 16 + blockIdx.y * 2 + half] = s;
        }
    }
}

// ---------------- softmax over t per batch row (sums the 16 partials) ----------
__global__ void softmax_k(const float* __restrict__ energ, float* __restrict__ out) {
    int b = blockIdx.x;
    int t = threadIdx.x;
    int wave = t >> 6, lane = t & 63;
    __shared__ float smax[4], ssum[4];
    float e[4];
#pragma unroll
    for (int i = 0; i < 4; i++) {
        size_t m = (size_t)b * TLEN + t + i * 256;
        const float* p = energ + m * 16;
        f32x4 p0 = *reinterpret_cast<const f32x4*>(p);
        f32x4 p1 = *reinterpret_cast<const f32x4*>(p + 4);
        f32x4 p2 = *reinterpret_cast<const f32x4*>(p + 8);
        f32x4 p3 = *reinterpret_cast<const f32x4*>(p + 12);
        e[i] = ((p0[0] + p0[1]) + (p0[2] + p0[3])) + ((p1[0] + p1[1]) + (p1[2] + p1[3]))
             + ((p2[0] + p2[1]) + (p2[2] + p2[3])) + ((p3[0] + p3[1]) + (p3[2] + p3[3]));
    }
    float m = fmaxf(fmaxf(e[0], e[1]), fmaxf(e[2], e[3]));
#pragma unroll
    for (int off = 32; off >= 1; off >>= 1) m = fmaxf(m, __shfl_xor(m, off));
    if (lane == 0) smax[wave] = m;
    __syncthreads();
    float M = fmaxf(fmaxf(smax[0], smax[1]), fmaxf(smax[2], smax[3]));
    float x[4]; float s = 0.f;
#pragma unroll
    for (int i = 0; i < 4; i++) { x[i] = __expf(e[i] - M); s += x[i]; }
#pragma unroll
    for (int off = 32; off >= 1; off >>= 1) s += __shfl_xor(s, off);
    if (lane == 0) ssum[wave] = s;
    __syncthreads();
    float S = ssum[0] + ssum[1] + ssum[2] + ssum[3];
    float inv = 1.f / S;
#pragma unroll
    for (int i = 0; i < 4; i++) out[b * TLEN + t + i * 256] = x[i] * inv;
}

extern "C" void kernel_launch(void* const* d_in, const int* in_sizes, int n_in,
                              void* d_out, int out_size, void* d_ws, size_t ws_size,
                              hipStream_t stream) {
    const float* hidden = (const float*)d_in[0];   // (1, 32, 1024) fp32
    const float* enc    = (const float*)d_in[1];   // (32, 1024, 1024) fp32
    const float* W      = (const float*)d_in[2];   // (1024, 2048) fp32
    const float* bias   = (const float*)d_in[3];   // (1024,) fp32
    const float* v      = (const float*)d_in[4];   // (1024,) fp32
    float* out = (float*)d_out;                    // (32, 1, 1024) fp32

    char* ws = (char*)d_ws;
    float*    q     = (float*)ws;                            // 128 KB
    float*    energ = (float*)(ws + 131072);                 // 2 MB (16 partials x M_TOT)
    _Float16* We16  = (_Float16*)(ws + 131072 + 2097152);    // 2 MB
    _Float16* enc16 = (_Float16*)(ws + 131072 + 2097152 + 2097152);  // 64 MB
    const size_t need_fast = 131072 + 2097152 + 2097152 + (size_t)M_TOT * HDIM * 2;  // ~68 MB

    if (ws_size >= need_fast) {
        // merged prep: We convert (1024) + qproj (1024) + enc convert (16384)
        prep_k<<<dim3(18432), 256, 0, stream>>>(W, hidden, bias, enc, We16, q, enc16);
        attn_gemm_lds_k<<<dim3(2048), 256, 0, stream>>>(enc16, We16, q, v, energ);
    } else {
        prep_k<<<dim3(2048), 256, 0, stream>>>(W, hidden, bias, enc, We16, q, enc16);
        attn_gemm_k<<<dim3(256, 8), 256, 0, stream>>>(enc, We16, q, v, energ);
    }
    softmax_k<<<dim3(BATCH), 256, 0, stream>>>(energ, out);
}

// Round 6
// 294.110 us; speedup vs baseline: 1.5817x; 1.0112x over previous
//
#include <hip/hip_runtime.h>
#include <hip/hip_fp16.h>

typedef _Float16 half8   __attribute__((ext_vector_type(8)));
typedef _Float16 half4_t __attribute__((ext_vector_type(4)));
typedef float    f32x4   __attribute__((ext_vector_type(4)));

#define HDIM  1024
#define BATCH 32
#define TLEN  1024
#define M_TOT (BATCH * TLEN)

#define BM 128
#define BN 128
#define LDA 40   // fallback-path padded LDS stride (halves)

// ---------------- merged prep:
//   blocks 0..1023     : We = W[:,H:] -> fp16 (g-major, k-contiguous)
//   blocks 1024..2047  : qproj  q[b][g] = bias[g] + sum_h hidden[b][h]*W[g][h]
//   blocks 2048..18431 : enc fp32 -> fp16 streaming convert (fast path only)
__global__ void prep_k(const float* __restrict__ W, const float* __restrict__ hidden,
                       const float* __restrict__ bias, const float* __restrict__ enc,
                       _Float16* __restrict__ We16, float* __restrict__ q,
                       _Float16* __restrict__ enc16) {
    const int bid = blockIdx.x;
    const int t = threadIdx.x;
    if (bid < 1024) {
        int idx = bid * 256 + t;
        int g  = idx >> 8;
        int k4 = idx & 255;
        float4 f = *reinterpret_cast<const float4*>(W + (size_t)g * 2048 + 1024 + k4 * 4);
        half4_t h;
        h[0] = (_Float16)f.x; h[1] = (_Float16)f.y; h[2] = (_Float16)f.z; h[3] = (_Float16)f.w;
        *reinterpret_cast<half4_t*>(We16 + (size_t)idx * 4) = h;
    } else if (bid < 2048) {
        int g = bid - 1024;
        int wave = t >> 6, lane = t & 63;
        float acc[BATCH];
#pragma unroll
        for (int b = 0; b < BATCH; b++) acc[b] = 0.f;
        const float* wr = W + (size_t)g * 2048;
        for (int h = t; h < HDIM; h += 256) {
            float w = wr[h];
#pragma unroll
            for (int b = 0; b < BATCH; b++) acc[b] = fmaf(w, hidden[b * HDIM + h], acc[b]);
        }
        __shared__ float sm[4 * BATCH];
#pragma unroll
        for (int b = 0; b < BATCH; b++) {
            float s = acc[b];
#pragma unroll
            for (int off = 32; off >= 1; off >>= 1) s += __shfl_xor(s, off);
            if (lane == 0) sm[wave * BATCH + b] = s;
        }
        __syncthreads();
        if (t < BATCH) {
            float s = sm[t] + sm[BATCH + t] + sm[2 * BATCH + t] + sm[3 * BATCH + t];
            q[t * HDIM + g] = s + bias[g];
        }
    } else {
        size_t i = ((size_t)(bid - 2048) * 256 + t) * 8;
        float4 f0 = *reinterpret_cast<const float4*>(enc + i);
        float4 f1 = *reinterpret_cast<const float4*>(enc + i + 4);
        half8 h;
        h[0] = (_Float16)f0.x; h[1] = (_Float16)f0.y; h[2] = (_Float16)f0.z; h[3] = (_Float16)f0.w;
        h[4] = (_Float16)f1.x; h[5] = (_Float16)f1.y; h[6] = (_Float16)f1.z; h[7] = (_Float16)f1.w;
        *reinterpret_cast<half8*>(enc16 + i) = h;
    }
}

__device__ __forceinline__ void async16(const void* g, void* l) {
    __builtin_amdgcn_global_load_lds(
        (const __attribute__((address_space(1))) void*)g,
        (__attribute__((address_space(3))) void*)l, 16, 0, 0);
}

// ---------------- FAST: 256x256 tile, BK=64, 8 waves, 8-phase counted-vmcnt (retry) ----
// Layout/swizzle identical to the correctness-verified round-1 kernel. Schedule fixes:
//  (1) fragments re-read per phase into aF[4][2]/bF[2][2] (48 VGPR live; B-lo re-read
//      at P4/P8) instead of 24 persistent half8 (~96 VGPR) -> off the 256-reg cliff.
//  (2) deeper prefetch: per-iteration stages {P1:B0(T1) P2:B1(T1) P4:A0,A1(T0+2)
//      P5:B0(T0+2) P6:B1(T0+2) P8:A0,A1(T1+2)}; vmcnt(4) at P4/P8 then waits only on
//      loads issued >=3 phases earlier. Overwrite-audit: buf0.A free after P3, buf0.B
//      after P4 (B-lo re-read), buf1.A after P7, buf1.B after P8 — all stage slots
//      are >=1 barrier after the last read of their region.
//  (3) lgkmcnt(8) pre-drain in the 12-read phases (P1/P5), per the m201 template.
// Tail: vmcnt(0) at P4 of the last iteration (counted wait would pass vacuously).
#define NIT 8    // 2 K-tiles/iter, BK=64 -> K = 1024

__global__ __launch_bounds__(512)
void attn_gemm8_k(const _Float16* __restrict__ enc16,
                  const _Float16* __restrict__ We16,
                  const float* __restrict__ q, const float* __restrict__ v,
                  float* __restrict__ energ) {
    __shared__ _Float16 lds[65536];   // [buf:2][A 16384 | B 16384] halves = 128 KB

    const int tid  = threadIdx.x;
    const int id   = blockIdx.x;
    const int xcd  = id & 7;
    const int w    = id >> 3;                 // 0..63
    const int m0   = (xcd * 16 + (w >> 2)) * 256;
    const int nblk = w & 3;
    const int n0   = nblk * 256;

    const int wave = tid >> 6;
    const int lane = tid & 63;
    const int quad = lane >> 4;
    const int l16  = lane & 15;
    const int wm   = wave >> 2;       // 0/1: rows wm*128
    const int wn   = wave & 3;        // 0..3: cols wn*64
    const int hb   = wn >> 1;

    // staging: thread covers (row = tid>>3 [+64], slot chunk c = tid&7); global chunk c^(row&7)
    const int rA = tid >> 3;
    const int sc = ((tid & 7) ^ (rA & 7)) * 8;
    const _Float16* gA = enc16 + (size_t)(m0 + rA) * HDIM + sc;
    const _Float16* gB = We16  + (size_t)(n0 + rA) * HDIM + sc;

    // fragment read addressing (round-1 verified): swizzled chunk = (ks*4+quad) ^ (l16&7)
    const int cs0 = (quad ^ (l16 & 7)) * 8;
    const int cs1 = ((4 + quad) ^ (l16 & 7)) * 8;
    const int arow = wm * 8192 + l16 * 64;
    const int brow = 16384 + hb * 8192 + ((wn & 1) * 64 + l16) * 64;

    f32x4 acc[8][4];
#pragma unroll
    for (int i = 0; i < 8; i++)
#pragma unroll
        for (int j = 0; j < 4; j++) acc[i][j] = {0.f, 0.f, 0.f, 0.f};

    half8 aF[4][2], bF[2][2];

#define STAGE_AH(buf, ha, kt) { \
    _Float16* d_ = &lds[(buf)*32768 + (ha)*8192 + tid*8]; \
    const _Float16* s_ = gA + (size_t)(ha)*131072 + (kt)*64; \
    async16(s_, d_); async16(s_ + 65536, d_ + 4096); }

#define STAGE_BH(buf, hh, kt) { \
    _Float16* d_ = &lds[(buf)*32768 + 16384 + (hh)*8192 + tid*8]; \
    const _Float16* s_ = gB + (size_t)(hh)*131072 + (kt)*64; \
    async16(s_, d_); async16(s_ + 65536, d_ + 4096); }

#define RD_A(bb, HO) { _Pragma("unroll") for (int mi_ = 0; mi_ < 4; mi_++) { \
    aF[mi_][0] = *reinterpret_cast<const half8*>(&lds[(bb)+arow+(mi_+HO)*1024+cs0]); \
    aF[mi_][1] = *reinterpret_cast<const half8*>(&lds[(bb)+arow+(mi_+HO)*1024+cs1]); } }

#define RD_B(bb, HO) { _Pragma("unroll") for (int ni_ = 0; ni_ < 2; ni_++) { \
    bF[ni_][0] = *reinterpret_cast<const half8*>(&lds[(bb)+brow+(ni_+HO)*1024+cs0]); \
    bF[ni_][1] = *reinterpret_cast<const half8*>(&lds[(bb)+brow+(ni_+HO)*1024+cs1]); } }

#define MFMA16(MO, NO) { _Pragma("unroll") for (int ks_ = 0; ks_ < 2; ks_++) \
    _Pragma("unroll") for (int mi_ = 0; mi_ < 4; mi_++) \
    _Pragma("unroll") for (int ni_ = 0; ni_ < 2; ni_++) \
      acc[mi_+MO][ni_+NO] = __builtin_amdgcn_mfma_f32_16x16x32_f16( \
          aF[mi_][ks_], bF[ni_][ks_], acc[mi_+MO][ni_+NO], 0, 0, 0); }

#define PH_MID { __builtin_amdgcn_s_barrier(); \
    asm volatile("s_waitcnt lgkmcnt(0)" ::: "memory"); \
    __builtin_amdgcn_sched_barrier(0); \
    __builtin_amdgcn_s_setprio(1); }
#define PH_END { __builtin_amdgcn_s_setprio(0); \
    __builtin_amdgcn_s_barrier(); \
    __builtin_amdgcn_sched_barrier(0); }

    // prologue: tile0 (all 4 halves) -> buf0; tile1 A-halves -> buf1. 12 loads; wait tile0.
    STAGE_AH(0, 0, 0); STAGE_AH(0, 1, 0); STAGE_BH(0, 0, 0); STAGE_BH(0, 1, 0);
    STAGE_AH(1, 0, 1); STAGE_AH(1, 1, 1);
    asm volatile("s_waitcnt vmcnt(4)" ::: "memory");
    __builtin_amdgcn_s_barrier();
    __builtin_amdgcn_sched_barrier(0);

    for (int i = 0; i < NIT; i++) {
        const bool more = (i < NIT - 1);
        const int t1 = 2 * i + 1, t2 = 2 * i + 2, t3 = 2 * i + 3;
        // ---- K-tile 2i from buf0 ----
        // P1
        RD_A(0, 0); RD_B(0, 0);  STAGE_BH(1, 0, t1);
        asm volatile("s_waitcnt lgkmcnt(8)" ::: "memory");
        PH_MID; MFMA16(0, 0); PH_END;
        // P2
        RD_B(0, 2);              STAGE_BH(1, 1, t1);
        PH_MID; MFMA16(0, 2); PH_END;
        // P3
        RD_A(0, 4);
        PH_MID; MFMA16(4, 2); PH_END;
        // P4  (B-lo re-read; stage next-next A into just-freed buf0.A)
        RD_B(0, 0);              if (more) { STAGE_AH(0, 0, t2); STAGE_AH(0, 1, t2); }
        PH_MID; MFMA16(4, 0);
        __builtin_amdgcn_s_setprio(0);
        if (more) { asm volatile("s_waitcnt vmcnt(4)" ::: "memory"); }
        else      { asm volatile("s_waitcnt vmcnt(0)" ::: "memory"); }
        __builtin_amdgcn_s_barrier();
        __builtin_amdgcn_sched_barrier(0);
        // ---- K-tile 2i+1 from buf1 ----
        // P5
        RD_A(32768, 0); RD_B(32768, 0);  if (more) STAGE_BH(0, 0, t2);
        asm volatile("s_waitcnt lgkmcnt(8)" ::: "memory");
        PH_MID; MFMA16(0, 0); PH_END;
        // P6
        RD_B(32768, 2);                  if (more) STAGE_BH(0, 1, t2);
        PH_MID; MFMA16(0, 2); PH_END;
        // P7
        RD_A(32768, 4);
        PH_MID; MFMA16(4, 2); PH_END;
        // P8
        RD_B(32768, 0);                  if (more) { STAGE_AH(1, 0, t3); STAGE_AH(1, 1, t3); }
        PH_MID; MFMA16(4, 0);
        __builtin_amdgcn_s_setprio(0);
        if (more) { asm volatile("s_waitcnt vmcnt(4)" ::: "memory"); }
        __builtin_amdgcn_s_barrier();
        __builtin_amdgcn_sched_barrier(0);
    }
#undef STAGE_AH
#undef STAGE_BH
#undef RD_A
#undef RD_B
#undef MFMA16
#undef PH_MID
#undef PH_END

    // epilogue (round-1 verified mapping): C/D col = l16, row = quad*4 + r.
    // 16 partials/row, slot = row*16 + nblk*4 + wn — exactly one writer per slot.
    const int bidx = m0 >> 10;
    const int gb = n0 + wn * 64;
    float qv[4], vv[4];
#pragma unroll
    for (int ni = 0; ni < 4; ni++) {
        int g = gb + ni * 16 + l16;
        qv[ni] = q[bidx * HDIM + g];
        vv[ni] = v[g];
    }
#pragma unroll
    for (int mi = 0; mi < 8; mi++) {
#pragma unroll
        for (int r = 0; r < 4; r++) {
            int row = m0 + wm * 128 + mi * 16 + quad * 4 + r;
            float s = 0.f;
#pragma unroll
            for (int ni = 0; ni < 4; ni++) {
                float pre = acc[mi][ni][r] + qv[ni];
                float e = __expf(2.f * pre);
                float th = 1.f - 2.f / (e + 1.f);
                s = fmaf(th, vv[ni], s);
            }
            s += __shfl_xor(s, 1);
            s += __shfl_xor(s, 2);
            s += __shfl_xor(s, 4);
            s += __shfl_xor(s, 8);
            if (l16 == 0) energ[(size_t)row * 16 + nblk * 4 + wn] = s;
        }
    }
}

// ---------------- FALLBACK: fp32 A on-the-fly convert (BK=32, padded LDS) ----------------
__global__ __launch_bounds__(256, 2)
void attn_gemm_k(const float* __restrict__ enc, const _Float16* __restrict__ We16,
                 const float* __restrict__ q, const float* __restrict__ v,
                 float* __restrict__ energ) {
    __shared__ _Float16 As[BM * LDA];
    __shared__ _Float16 Bs[BN * LDA];

    const int tid  = threadIdx.x;
    const int m0   = blockIdx.x * BM;
    const int n0   = blockIdx.y * BN;
    const int wave = tid >> 6;
    const int lane = tid & 63;
    const int quad = lane >> 4;
    const int l16  = lane & 15;
    const int wm   = (wave & 1) * 64;
    const int wn   = (wave >> 1) * 64;

    const int srow = tid >> 1;
    const int scol = (tid & 1) * 16;

    f32x4 acc[4][4];
#pragma unroll
    for (int i = 0; i < 4; i++)
#pragma unroll
        for (int j = 0; j < 4; j++) acc[i][j] = {0.f, 0.f, 0.f, 0.f};

    const float*    ag = enc  + (size_t)(m0 + srow) * HDIM + scol;
    const _Float16* bg = We16 + (size_t)(n0 + srow) * HDIM + scol;
    _Float16* aw = &As[srow * LDA + scol];
    _Float16* bw = &Bs[srow * LDA + scol];

    for (int k0 = 0; k0 < HDIM; k0 += 32) {
        float4 a0 = *reinterpret_cast<const float4*>(ag + k0 + 0);
        float4 a1 = *reinterpret_cast<const float4*>(ag + k0 + 4);
        float4 a2 = *reinterpret_cast<const float4*>(ag + k0 + 8);
        float4 a3 = *reinterpret_cast<const float4*>(ag + k0 + 12);
        float4 b0 = *reinterpret_cast<const float4*>(bg + k0);
        float4 b1 = *reinterpret_cast<const float4*>(bg + k0 + 8);

        __syncthreads();

        half8 ha0, ha1;
        ha0[0] = (_Float16)a0.x; ha0[1] = (_Float16)a0.y; ha0[2] = (_Float16)a0.z; ha0[3] = (_Float16)a0.w;
        ha0[4] = (_Float16)a1.x; ha0[5] = (_Float16)a1.y; ha0[6] = (_Float16)a1.z; ha0[7] = (_Float16)a1.w;
        ha1[0] = (_Float16)a2.x; ha1[1] = (_Float16)a2.y; ha1[2] = (_Float16)a2.z; ha1[3] = (_Float16)a2.w;
        ha1[4] = (_Float16)a3.x; ha1[5] = (_Float16)a3.y; ha1[6] = (_Float16)a3.z; ha1[7] = (_Float16)a3.w;
        *reinterpret_cast<half8*>(aw)     = ha0;
        *reinterpret_cast<half8*>(aw + 8) = ha1;
        *reinterpret_cast<float4*>(bw)     = b0;
        *reinterpret_cast<float4*>(bw + 8) = b1;

        __syncthreads();

        half8 af[4], bf[4];
#pragma unroll
        for (int i = 0; i < 4; i++) {
            af[i] = *reinterpret_cast<const half8*>(&As[(wm + i * 16 + l16) * LDA + quad * 8]);
            bf[i] = *reinterpret_cast<const half8*>(&Bs[(wn + i * 16 + l16) * LDA + quad * 8]);
        }
#pragma unroll
        for (int mi = 0; mi < 4; mi++)
#pragma unroll
            for (int ni = 0; ni < 4; ni++)
                acc[mi][ni] = __builtin_amdgcn_mfma_f32_16x16x32_f16(af[mi], bf[ni], acc[mi][ni], 0, 0, 0);
    }

    const int bidx = m0 >> 10;
    const int half = wn >> 6;
    float qv[4], vv[4];
#pragma unroll
    for (int ni = 0; ni < 4; ni++) {
        int g = n0 + wn + ni * 16 + l16;
        qv[ni] = q[bidx * HDIM + g];
        vv[ni] = v[g];
    }
#pragma unroll
    for (int mi = 0; mi < 4; mi++) {
#pragma unroll
        for (int r = 0; r < 4; r++) {
            int row = wm + mi * 16 + quad * 4 + r;
            float s = 0.f;
#pragma unroll
            for (int ni = 0; ni < 4; ni++) {
                float pre = acc[mi][ni][r] + qv[ni];
                float e = __expf(2.f * pre);
                float th = 1.f - 2.f / (e + 1.f);
                s = fmaf(th, vv[ni], s);
            }
            s += __shfl_xor(s, 1);
            s += __shfl_xor(s, 2);
            s += __shfl_xor(s, 4);
            s += __shfl_xor(s, 8);
            if (l16 == 0) energ[(size_t)(m0 + row) * 16 + blockIdx.y * 2 + half] = s;
        }
    }
}

// ---------------- softmax over t per batch row (sums the 16 partials) ----------
__global__ void softmax_k(const float* __restrict__ energ, float* __restrict__ out) {
    int b = blockIdx.x;
    int t = threadIdx.x;
    int wave = t >> 6, lane = t & 63;
    __shared__ float smax[4], ssum[4];
    float e[4];
#pragma unroll
    for (int i = 0; i < 4; i++) {
        size_t m = (size_t)b * TLEN + t + i * 256;
        const float* p = energ + m * 16;
        f32x4 p0 = *reinterpret_cast<const f32x4*>(p);
        f32x4 p1 = *reinterpret_cast<const f32x4*>(p + 4);
        f32x4 p2 = *reinterpret_cast<const f32x4*>(p + 8);
        f32x4 p3 = *reinterpret_cast<const f32x4*>(p + 12);
        e[i] = ((p0[0] + p0[1]) + (p0[2] + p0[3])) + ((p1[0] + p1[1]) + (p1[2] + p1[3]))
             + ((p2[0] + p2[1]) + (p2[2] + p2[3])) + ((p3[0] + p3[1]) + (p3[2] + p3[3]));
    }
    float m = fmaxf(fmaxf(e[0], e[1]), fmaxf(e[2], e[3]));
#pragma unroll
    for (int off = 32; off >= 1; off >>= 1) m = fmaxf(m, __shfl_xor(m, off));
    if (lane == 0) smax[wave] = m;
    __syncthreads();
    float M = fmaxf(fmaxf(smax[0], smax[1]), fmaxf(smax[2], smax[3]));
    float x[4]; float s = 0.f;
#pragma unroll
    for (int i = 0; i < 4; i++) { x[i] = __expf(e[i] - M); s += x[i]; }
#pragma unroll
    for (int off = 32; off >= 1; off >>= 1) s += __shfl_xor(s, off);
    if (lane == 0) ssum[wave] = s;
    __syncthreads();
    float S = ssum[0] + ssum[1] + ssum[2] + ssum[3];
    float inv = 1.f / S;
#pragma unroll
    for (int i = 0; i < 4; i++) out[b * TLEN + t + i * 256] = x[i] * inv;
}

extern "C" void kernel_launch(void* const* d_in, const int* in_sizes, int n_in,
                              void* d_out, int out_size, void* d_ws, size_t ws_size,
                              hipStream_t stream) {
    const float* hidden = (const float*)d_in[0];   // (1, 32, 1024) fp32
    const float* enc    = (const float*)d_in[1];   // (32, 1024, 1024) fp32
    const float* W      = (const float*)d_in[2];   // (1024, 2048) fp32
    const float* bias   = (const float*)d_in[3];   // (1024,) fp32
    const float* v      = (const float*)d_in[4];   // (1024,) fp32
    float* out = (float*)d_out;                    // (32, 1, 1024) fp32

    char* ws = (char*)d_ws;
    float*    q     = (float*)ws;                            // 128 KB
    float*    energ = (float*)(ws + 131072);                 // 2 MB (16 partials x M_TOT)
    _Float16* We16  = (_Float16*)(ws + 131072 + 2097152);    // 2 MB
    _Float16* enc16 = (_Float16*)(ws + 131072 + 2097152 + 2097152);  // 64 MB
    const size_t need_fast = 131072 + 2097152 + 2097152 + (size_t)M_TOT * HDIM * 2;  // ~68 MB

    if (ws_size >= need_fast) {
        prep_k<<<dim3(18432), 256, 0, stream>>>(W, hidden, bias, enc, We16, q, enc16);
        attn_gemm8_k<<<dim3(512), 512, 0, stream>>>(enc16, We16, q, v, energ);
    } else {
        prep_k<<<dim3(2048), 256, 0, stream>>>(W, hidden, bias, enc, We16, q, enc16);
        attn_gemm_k<<<dim3(256, 8), 256, 0, stream>>>(enc, We16, q, v, energ);
    }
    softmax_k<<<dim3(BATCH), 256, 0, stream>>>(energ, out);
}